// Round 9
// baseline (299.409 us; speedup 1.0000x reference)
//
#include <hip/hip_runtime.h>
#include <cstddef>

// Problem constants: B=32, N=4096, D=256, K=8 slots, S=16, H=128, 3 iters.

typedef unsigned short ushort_t;
typedef __attribute__((ext_vector_type(8))) short short8;   // 8 bf16 = 4 VGPRs
typedef __attribute__((ext_vector_type(4))) float f32x4;

__device__ __forceinline__ float sigmoid_f(float x){ return 1.f/(1.f+__expf(-x)); }
__device__ __forceinline__ float tanh_f(float x){ return 1.f - 2.f/(__expf(2.f*x)+1.f); }

// fp32 -> bf16 (RNE), as raw bits (weights + mt consistency)
__device__ __forceinline__ ushort_t f2bf(float x){
  unsigned u = __float_as_uint(x);
  return (ushort_t)((u + 0x7FFFu + ((u>>16)&1u)) >> 16);
}
__device__ __forceinline__ float bf2f(ushort_t b){
  return __uint_as_float(((unsigned)b) << 16);
}
// truncation hi/lo split (cheap: AND/SUB/SHR), combined rel err ~2^-17
__device__ __forceinline__ void split_bf(float v, short& hi, short& lo){
  unsigned u = __float_as_uint(v);
  hi = (short)(u >> 16);
  float hf = __uint_as_float(u & 0xFFFF0000u);
  lo = (short)(__float_as_uint(v - hf) >> 16);
}

// async global->LDS, 16 B per lane; lds dest = wave-uniform base + lane*16.
__device__ __forceinline__ void load16_to_lds(const float* g, float* l) {
  __builtin_amdgcn_global_load_lds(
      (const __attribute__((address_space(1))) unsigned int*)g,
      (__attribute__((address_space(3))) unsigned int*)l,
      16, 0, 0);
}

// ---------------- K0: prep (bf16-split weights, init slots, q1, zeros) -----
__global__ __launch_bounds__(256) void k_prep(
    const float* __restrict__ lnw, const float* __restrict__ lnb,
    const float* __restrict__ wk, const float* __restrict__ wv,
    const float* __restrict__ init_slots,
    const float* __restrict__ ln_s_w, const float* __restrict__ ln_s_b,
    const float* __restrict__ wq,
    ushort_t* __restrict__ Wh, ushort_t* __restrict__ Wl,
    float* __restrict__ mt,
    float* __restrict__ qbuf, float* __restrict__ upd, float* __restrict__ Abuf,
    float* __restrict__ slots_out)
{
  int t = threadIdx.x;
  int i = blockIdx.x*256 + t;          // 32*256 == 8192 exactly
  {
    int s = i >> 8, d = i & 255;
    float w = (s < 16) ? wk[s*256+d] : wv[(s-16)*256+d];
    float w0 = lnw[d]*w;
    ushort_t hb = f2bf(w0);
    ushort_t lb = f2bf(w0 - bf2f(hb));
    Wh[i] = hb; Wl[i] = lb;
  }
  if (blockIdx.x != 0) return;
  // m[s] from QUANTIZED weights; t[s] exact fp32
  {
    int s = t >> 3, j = t & 7;
    float m = 0.f, tv = 0.f;
    for (int d = j; d < 256; d += 8) {
      float w = (s < 16) ? wk[s*256+d] : wv[(s-16)*256+d];
      float w0 = lnw[d]*w;
      ushort_t hb = f2bf(w0);
      float hf = bf2f(hb);
      float lf = bf2f(f2bf(w0 - hf));
      m  += hf + lf;
      tv  = fmaf(lnb[d], w, tv);
    }
    m += __shfl_xor(m,1);  m += __shfl_xor(m,2);  m += __shfl_xor(m,4);
    tv += __shfl_xor(tv,1); tv += __shfl_xor(tv,2); tv += __shfl_xor(tv,4);
    if (j == 0) { mt[s] = m; mt[32+s] = tv; }
  }
  #pragma unroll
  for (int j2 = 0; j2 < 16; ++j2) {
    slots_out[t*16+j2] = init_slots[t*16+j2];
    upd[t*16+j2] = 0.f;
  }
  Abuf[t] = 0.f;
  // q for iteration 1: thread t = (b,k) row
  float sl[16];
  #pragma unroll
  for (int j2 = 0; j2 < 16; ++j2) sl[j2] = init_slots[t*16+j2];
  float mu = 0.f;
  #pragma unroll
  for (int j2 = 0; j2 < 16; ++j2) mu += sl[j2];
  mu *= (1.f/16.f);
  float var = 0.f;
  #pragma unroll
  for (int j2 = 0; j2 < 16; ++j2) { float d = sl[j2]-mu; var = fmaf(d,d,var); }
  var *= (1.f/16.f);
  float rstd = rsqrtf(var + 1e-5f);
  float y[16];
  #pragma unroll
  for (int j2 = 0; j2 < 16; ++j2) y[j2] = (sl[j2]-mu)*rstd*ln_s_w[j2] + ln_s_b[j2];
  #pragma unroll
  for (int tq = 0; tq < 16; ++tq) {
    float q = 0.f;
    #pragma unroll
    for (int s2 = 0; s2 < 16; ++s2) q = fmaf(y[s2], wq[tq*16+s2], q);
    qbuf[t*16+tq] = q;
  }
}

// ---------------- K1: fused LayerNorm + K/V projection (one-shot LDS) ------
// Block = 256 threads = 4 waves, 64 rows. The WHOLE 64x256 x-tile (64 KB) is
// staged in one shot: one global_load_lds per ROW (contiguous 1 KB source;
// per-lane rotation *within* the row keeps the read swizzle conflict-free:
// (row, chunk c, colblock cb) lives at LDS word row*256 + c*64 +
// ((cb+row)&15)*4). 16 instrs/wave in flight -> latency amortized once, then
// ONE barrier, then all 8 K-steps uninterrupted (the R8 killer: 4 barriers
// each draining ~900cyc of freshly-issued loads). bf16 VGPR weight frags,
// mfma_f32_16x16x32_bf16 hi/lo split (3 passes), LN folded at epilogue.
__global__ __launch_bounds__(256) void k_proj(
    const float* __restrict__ x, const ushort_t* __restrict__ Wh,
    const ushort_t* __restrict__ Wl, const float* __restrict__ mt,
    float* __restrict__ kout, float* __restrict__ vout)
{
  __shared__ float xs[64*256];        // 64 KiB -> 2 blocks/CU
  int t = threadIdx.x;
  int lane = t & 63;
  int p = __builtin_amdgcn_readfirstlane(t >> 6);
  int m = lane & 15, quad = lane >> 4;
  int r0 = blockIdx.x*64;
  const float* xbase = x + (size_t)r0*256;

  // weight frag pointers: B[n=m][k=quad*8+j], load at kk*32
  const ushort_t* whk = Wh + (size_t)m*256 + quad*8;
  const ushort_t* whv = whk + 16*256;
  const ushort_t* wlk = Wl + (size_t)m*256 + quad*8;
  const ushort_t* wlv = wlk + 16*256;

  // stage: wave p issues one instr per row (rows p*16..p*16+15).
  // lane l covers chunk c = l>>4, slot = l&15 -> global cb = (slot - row)&15.
  {
    int c = lane >> 4, slot = lane & 15;
    #pragma unroll
    for (int i = 0; i < 16; ++i) {
      int row = p*16 + i;
      int cb = (slot - row) & 15;
      load16_to_lds(xbase + (size_t)row*256 + c*64 + cb*4, &xs[row*256]);
    }
  }
  __syncthreads();                    // single drain for the whole tile

  f32x4 acck = {0.f,0.f,0.f,0.f}, accv = {0.f,0.f,0.f,0.f};
  float sum = 0.f, sumsq = 0.f;
  int rowA = p*16 + m;
  const float* xrow = &xs[rowA*256];

  #pragma unroll
  for (int kk = 0; kk < 8; ++kk) {
    int c = kk >> 1, ks = kk & 1;
    short8 bh_k = *(const short8*)(whk + kk*32);
    short8 bh_v = *(const short8*)(whv + kk*32);
    short8 bl_k = *(const short8*)(wlk + kk*32);
    short8 bl_v = *(const short8*)(wlv + kk*32);
    int cbA = ks*8 + quad*2;
    float4 f0 = *(const float4*)&xrow[c*64 + (((cbA  ) + m) & 15)*4];
    float4 f1 = *(const float4*)&xrow[c*64 + (((cbA+1) + m) & 15)*4];
    float xv[8] = {f0.x,f0.y,f0.z,f0.w, f1.x,f1.y,f1.z,f1.w};
    short8 ah, al;
    #pragma unroll
    for (int j = 0; j < 8; ++j) {
      float v = xv[j];
      sum += v; sumsq = fmaf(v, v, sumsq);
      short h_, l_;
      split_bf(v, h_, l_);
      ah[j] = h_; al[j] = l_;
    }
    acck = __builtin_amdgcn_mfma_f32_16x16x32_bf16(ah, bh_k, acck, 0, 0, 0);
    accv = __builtin_amdgcn_mfma_f32_16x16x32_bf16(ah, bh_v, accv, 0, 0, 0);
    acck = __builtin_amdgcn_mfma_f32_16x16x32_bf16(al, bh_k, acck, 0, 0, 0);
    accv = __builtin_amdgcn_mfma_f32_16x16x32_bf16(al, bh_v, accv, 0, 0, 0);
    acck = __builtin_amdgcn_mfma_f32_16x16x32_bf16(ah, bl_k, acck, 0, 0, 0);
    accv = __builtin_amdgcn_mfma_f32_16x16x32_bf16(ah, bl_v, accv, 0, 0, 0);
  }

  // full row stats (each quad covered 64 of 256 cols)
  sum   += __shfl_xor(sum, 16);  sum   += __shfl_xor(sum, 32);
  sumsq += __shfl_xor(sumsq, 16); sumsq += __shfl_xor(sumsq, 32);

  float mtk  = mt[m],    mtv  = mt[16+m];
  float mtkb = mt[32+m], mtvb = mt[48+m];
  #pragma unroll
  for (int r = 0; r < 4; ++r) {
    int row = quad*4 + r;
    float s_ = __shfl(sum,   row);
    float q_ = __shfl(sumsq, row);
    float mu = s_*(1.f/256.f);
    float var = q_*(1.f/256.f) - mu*mu;
    float rstd = rsqrtf(var + 1e-5f);
    float ok = fmaf(rstd, acck[r] - mu*mtk, mtkb);
    float ov = fmaf(rstd, accv[r] - mu*mtv, mtvb);
    size_t grow = (size_t)(r0 + p*16 + row)*16 + m;
    kout[grow] = ok;
    vout[grow] = ov;
  }
}

// ---------------- K2: logits + softmax-over-slots + MFMA update ------------
// (R8 version, verified.) k direct global->regs; v/p staged as bf16 hi/lo
// transposed tiles (stride 264); updates = P.V via 24 MFMA in wave 0.
__global__ __launch_bounds__(256) void k_attn(
    const float* __restrict__ kproj, const float* __restrict__ vproj,
    const float* __restrict__ qbuf,
    float* __restrict__ upd, float* __restrict__ Abuf,
    float* __restrict__ attn_out, int write_attn)
{
  __shared__ ushort_t vt[32*264];   // rows 0..15 = v_hi[s][n], 16..31 = v_lo
  __shared__ ushort_t pt[32*264];   // rows 0..7 = p_hi[kk][n], 16..23 = p_lo
  __shared__ float qs[128];
  __shared__ float apart[4][8];
  int b = blockIdx.x >> 4;
  int n0 = (blockIdx.x & 15) * 256;
  int t = threadIdx.x;
  int w = t >> 6, lane = t & 63;

  if (t < 128) qs[t] = qbuf[b*128 + t];

  const float* kr = kproj + ((size_t)(b*4096 + n0 + t))*16;
  const float* vr = vproj + ((size_t)(b*4096 + n0 + t))*16;
  float kv[16], vv[16];
  #pragma unroll
  for (int j = 0; j < 16; j += 4) {
    float4 f = *(const float4*)(kr+j);
    kv[j]=f.x; kv[j+1]=f.y; kv[j+2]=f.z; kv[j+3]=f.w;
    float4 g = *(const float4*)(vr+j);
    vv[j]=g.x; vv[j+1]=g.y; vv[j+2]=g.z; vv[j+3]=g.w;
  }
  #pragma unroll
  for (int s = 0; s < 16; ++s) {
    short h_, l_;
    split_bf(vv[s], h_, l_);
    vt[s*264 + t] = (ushort_t)h_;
    vt[(16+s)*264 + t] = (ushort_t)l_;
  }
  __syncthreads();   // qs ready

  float p8[8];
  {
    float lg[8];
    #pragma unroll
    for (int kk = 0; kk < 8; ++kk) {
      float a = 0.f;
      #pragma unroll
      for (int s = 0; s < 16; ++s) a = fmaf(qs[kk*16+s], kv[s], a);
      lg[kk] = a*0.25f;  // scale = 16^-0.5
    }
    float mx = lg[0];
    #pragma unroll
    for (int kk = 1; kk < 8; ++kk) mx = fmaxf(mx, lg[kk]);
    float se = 0.f;
    #pragma unroll
    for (int kk = 0; kk < 8; ++kk) { lg[kk] = __expf(lg[kk]-mx); se += lg[kk]; }
    float inv = 1.f/se;
    #pragma unroll
    for (int kk = 0; kk < 8; ++kk) {
      float pv = fmaf(lg[kk], inv, 1e-8f);   // softmax + EPS (pre-renorm)
      p8[kk] = pv;
      if (write_attn) attn_out[((size_t)(b*8+kk))*4096 + n0 + t] = pv;
    }
  }
  #pragma unroll
  for (int kk = 0; kk < 8; ++kk) {
    float r = p8[kk];
    r += __shfl_xor(r, 1);  r += __shfl_xor(r, 2);  r += __shfl_xor(r, 4);
    r += __shfl_xor(r, 8);  r += __shfl_xor(r, 16); r += __shfl_xor(r, 32);
    if (lane == 0) apart[w][kk] = r;
  }
  #pragma unroll
  for (int kk = 0; kk < 8; ++kk) {
    short h_, l_;
    split_bf(p8[kk], h_, l_);
    pt[kk*264 + t] = (ushort_t)h_;
    pt[(16+kk)*264 + t] = (ushort_t)l_;
  }
  __syncthreads();

  if (t < 8)
    atomicAdd(Abuf + b*8 + t,
              apart[0][t] + apart[1][t] + apart[2][t] + apart[3][t]);

  if (w == 0) {   // wave 0: updates = P . V via MFMA
    int m = lane & 15, quad = lane >> 4;
    const short8 z8 = {0,0,0,0,0,0,0,0};
    f32x4 acc = {0.f,0.f,0.f,0.f};
    #pragma unroll
    for (int c = 0; c < 8; ++c) {
      int k0 = c*32 + quad*8;
      short8 ah = (m < 8) ? *(const short8*)&pt[m*264 + k0]      : z8;
      short8 al = (m < 8) ? *(const short8*)&pt[(16+m)*264 + k0] : z8;
      short8 bh = *(const short8*)&vt[m*264 + k0];
      short8 bl = *(const short8*)&vt[(16+m)*264 + k0];
      acc = __builtin_amdgcn_mfma_f32_16x16x32_bf16(ah, bh, acc, 0, 0, 0);
      acc = __builtin_amdgcn_mfma_f32_16x16x32_bf16(al, bh, acc, 0, 0, 0);
      acc = __builtin_amdgcn_mfma_f32_16x16x32_bf16(ah, bl, acc, 0, 0, 0);
    }
    int s = lane & 15;
    #pragma unroll
    for (int r = 0; r < 4; ++r) {
      int kk = quad*4 + r;
      if (kk < 8) atomicAdd(upd + (b*8+kk)*16 + s, acc[r]);
    }
  }
}

// -------- GRU cell + LN + MLP body (shared by k_gru and k_final) -----------
// Assumes 16-lane group per (b,k); weights staged in the given LDS arrays.
__device__ __forceinline__ void gru_body(
    int bk, int s, int laneBase, int prep_next,
    float* upd, float* Abuf, float* slots, float* qbuf,
    const float* s_wih, const float* s_whh,
    const float* s_bih, const float* s_bhh,
    const float* s_w1, const float* s_b1,
    const float* s_w2, const float* s_b2,
    const float* s_lnmw, const float* s_lnmb,
    const float* s_lnsw, const float* s_lnsb, const float* s_wq)
{
  float inv = 1.f / Abuf[bk];
  float u[16], h[16];
  #pragma unroll
  for (int j = 0; j < 16; ++j) {
    u[j] = upd[bk*16+j] * inv;
    h[j] = slots[bk*16+j];
  }
  float hs = slots[bk*16+s];

  float gir = s_bih[s],  giz = s_bih[16+s], gin = s_bih[32+s];
  float ghr = s_bhh[s],  ghz = s_bhh[16+s], ghn = s_bhh[32+s];
  #pragma unroll
  for (int j = 0; j < 16; ++j) {
    gir = fmaf(u[j], s_wih[s*17+j], gir);
    giz = fmaf(u[j], s_wih[(16+s)*17+j], giz);
    gin = fmaf(u[j], s_wih[(32+s)*17+j], gin);
    ghr = fmaf(h[j], s_whh[s*17+j], ghr);
    ghz = fmaf(h[j], s_whh[(16+s)*17+j], ghz);
    ghn = fmaf(h[j], s_whh[(32+s)*17+j], ghn);
  }
  float rr = sigmoid_f(gir + ghr);
  float zz = sigmoid_f(giz + ghz);
  float nn = tanh_f(gin + rr*ghn);
  float hn = (1.f-zz)*nn + zz*hs;

  float ssum = hn;
  #pragma unroll
  for (int mm = 1; mm < 16; mm <<= 1) ssum += __shfl_xor(ssum, mm);
  float mu = ssum*(1.f/16.f);
  float dv = hn - mu;
  float vs = dv*dv;
  #pragma unroll
  for (int mm = 1; mm < 16; mm <<= 1) vs += __shfl_xor(vs, mm);
  float rstd = rsqrtf(vs*(1.f/16.f) + 1e-5f);
  float y = dv*rstd*s_lnmw[s] + s_lnmb[s];

  float yv[16];
  #pragma unroll
  for (int j = 0; j < 16; ++j) yv[j] = __shfl(y, laneBase + j);

  float h1[8];
  #pragma unroll
  for (int i = 0; i < 8; ++i) {
    int jj = i*16 + s;
    float a = s_b1[jj];
    #pragma unroll
    for (int q = 0; q < 16; ++q) a = fmaf(yv[q], s_w1[jj*17+q], a);
    h1[i] = fmaxf(a, 0.f);
  }
  float o = s_b2[s];
  #pragma unroll
  for (int i = 0; i < 8; ++i) {
    #pragma unroll
    for (int sp = 0; sp < 16; ++sp) {
      float hv = __shfl(h1[i], laneBase + sp);
      o = fmaf(hv, s_w2[s*129 + i*16 + sp], o);
    }
  }
  float slot_new = hn + o;
  slots[bk*16+s] = slot_new;

  if (prep_next) {
    float ss = slot_new;
    #pragma unroll
    for (int mm = 1; mm < 16; mm <<= 1) ss += __shfl_xor(ss, mm);
    float mu2 = ss*(1.f/16.f);
    float d2 = slot_new - mu2;
    float v2 = d2*d2;
    #pragma unroll
    for (int mm = 1; mm < 16; mm <<= 1) v2 += __shfl_xor(v2, mm);
    float rstd2 = rsqrtf(v2*(1.f/16.f) + 1e-5f);
    float y2 = d2*rstd2*s_lnsw[s] + s_lnsb[s];
    float qv = 0.f;
    #pragma unroll
    for (int sp = 0; sp < 16; ++sp)
      qv = fmaf(__shfl(y2, laneBase+sp), s_wq[s*17+sp], qv);
    qbuf[bk*16+s] = qv;
    upd[bk*16+s] = 0.f;
    if (s == 0) Abuf[bk] = 0.f;
  }
}

#define GRU_STAGE_LDS()                                                      \
  __shared__ float s_wih[48*17], s_whh[48*17];                               \
  __shared__ float s_bih[48], s_bhh[48];                                     \
  __shared__ float s_w1[128*17], s_b1[128];                                  \
  __shared__ float s_w2[16*129], s_b2[16];                                   \
  __shared__ float s_lnmw[16], s_lnmb[16], s_lnsw[16], s_lnsb[16];           \
  __shared__ float s_wq[16*17];                                              \
  {                                                                          \
    int t_ = threadIdx.x;                                                    \
    for (int i = t_; i < 768; i += 256) {                                    \
      int g = i >> 4, j = i & 15;                                            \
      s_wih[g*17+j] = w_ih[i];                                               \
      s_whh[g*17+j] = w_hh[i];                                               \
    }                                                                        \
    for (int i = t_; i < 2048; i += 256) {                                   \
      int r = i >> 4, c = i & 15;                                            \
      s_w1[r*17+c] = mlp_w1[i];                                              \
      int r2 = i >> 7, c2 = i & 127;                                         \
      s_w2[r2*129+c2] = mlp_w2[i];                                           \
    }                                                                        \
    if (t_ < 48) { s_bih[t_] = b_ih[t_]; s_bhh[t_] = b_hh[t_]; }             \
    if (t_ < 128) s_b1[t_] = mlp_b1[t_];                                     \
    if (t_ < 16) {                                                           \
      s_b2[t_] = mlp_b2[t_];                                                 \
      s_lnmw[t_] = ln_m_w[t_]; s_lnmb[t_] = ln_m_b[t_];                      \
      s_lnsw[t_] = ln_s_w[t_]; s_lnsb[t_] = ln_s_b[t_];                      \
    }                                                                        \
    for (int i = t_; i < 256; i += 256) {                                    \
      int r = i >> 4, c = i & 15;                                            \
      s_wq[r*17+c] = wq[i];                                                  \
    }                                                                        \
  }                                                                          \
  __syncthreads();

// ---------------- K3: GRU for iterations 0,1 (16 blocks) -------------------
__global__ __launch_bounds__(256) void k_gru(
    float* __restrict__ upd, float* __restrict__ Abuf,
    float* __restrict__ slots, float* __restrict__ qbuf,
    const float* __restrict__ w_ih, const float* __restrict__ w_hh,
    const float* __restrict__ b_ih, const float* __restrict__ b_hh,
    const float* __restrict__ mlp_w1, const float* __restrict__ mlp_b1,
    const float* __restrict__ mlp_w2, const float* __restrict__ mlp_b2,
    const float* __restrict__ ln_m_w, const float* __restrict__ ln_m_b,
    const float* __restrict__ ln_s_w, const float* __restrict__ ln_s_b,
    const float* __restrict__ wq)
{
  GRU_STAGE_LDS()
  int t = threadIdx.x;
  int bk = blockIdx.x*16 + (t >> 4);
  int s = t & 15;
  int laneBase = (t & 63) & ~15;
  gru_body(bk, s, laneBase, 1, upd, Abuf, slots, qbuf,
           s_wih, s_whh, s_bih, s_bhh, s_w1, s_b1, s_w2, s_b2,
           s_lnmw, s_lnmb, s_lnsw, s_lnsb, s_wq);
}

// ---------------- K4: final GRU (it 2) + attn normalization (fused) --------
// 256 blocks: every block scales its attn row by 1/A[bk]; blocks 0..15 also
// run the final GRU/MLP (prep_next=0) for their 16 (b,k) rows.
__global__ __launch_bounds__(256) void k_final(
    float* __restrict__ upd, float* __restrict__ Abuf,
    float* __restrict__ slots, float* __restrict__ qbuf,
    float* __restrict__ attn,
    const float* __restrict__ w_ih, const float* __restrict__ w_hh,
    const float* __restrict__ b_ih, const float* __restrict__ b_hh,
    const float* __restrict__ mlp_w1, const float* __restrict__ mlp_b1,
    const float* __restrict__ mlp_w2, const float* __restrict__ mlp_b2,
    const float* __restrict__ ln_m_w, const float* __restrict__ ln_m_b,
    const float* __restrict__ ln_s_w, const float* __restrict__ ln_s_b,
    const float* __restrict__ wq)
{
  int t = threadIdx.x;
  {
    int bk = blockIdx.x;
    float inv = 1.f / Abuf[bk];
    float4* p = (float4*)(attn + (size_t)bk*4096);
    #pragma unroll 4
    for (int i = t; i < 1024; i += 256) {
      float4 v = p[i];
      v.x *= inv; v.y *= inv; v.z *= inv; v.w *= inv;
      p[i] = v;
    }
  }
  if (blockIdx.x >= 16) return;
  GRU_STAGE_LDS()
  int bk = blockIdx.x*16 + (t >> 4);
  int s = t & 15;
  int laneBase = (t & 63) & ~15;
  gru_body(bk, s, laneBase, 0, upd, Abuf, slots, qbuf,
           s_wih, s_whh, s_bih, s_bhh, s_w1, s_b1, s_w2, s_b2,
           s_lnmw, s_lnmb, s_lnsw, s_lnsb, s_wq);
}

extern "C" void kernel_launch(void* const* d_in, const int* in_sizes, int n_in,
                              void* d_out, int out_size, void* d_ws, size_t ws_size,
                              hipStream_t stream)
{
  const float* inputs     = (const float*)d_in[0];
  const float* init_slots = (const float*)d_in[1];
  const float* ln_in_w    = (const float*)d_in[2];
  const float* ln_in_b    = (const float*)d_in[3];
  const float* ln_s_w     = (const float*)d_in[4];
  const float* ln_s_b     = (const float*)d_in[5];
  const float* ln_m_w     = (const float*)d_in[6];
  const float* ln_m_b     = (const float*)d_in[7];
  const float* wq         = (const float*)d_in[8];
  const float* wk         = (const float*)d_in[9];
  const float* wv         = (const float*)d_in[10];
  const float* w_ih       = (const float*)d_in[11];
  const float* w_hh       = (const float*)d_in[12];
  const float* b_ih       = (const float*)d_in[13];
  const float* b_hh       = (const float*)d_in[14];
  const float* mlp_w1     = (const float*)d_in[15];
  const float* mlp_b1     = (const float*)d_in[16];
  const float* mlp_w2     = (const float*)d_in[17];
  const float* mlp_b2     = (const float*)d_in[18];

  float* ws    = (float*)d_ws;
  ushort_t* Wh = (ushort_t*)ws;            // 8192 ushorts
  ushort_t* Wl = (ushort_t*)(ws + 4096);   // 8192 ushorts
  float* mt    = ws + 8192;          // 64
  float* qbuf  = ws + 8320;          // 4096
  float* upd   = ws + 12416;         // 4096
  float* Abuf  = ws + 16512;         // 256
  float* kproj = ws + 16768;         // 2097152
  float* vproj = kproj + 2097152;    // 2097152

  float* out   = (float*)d_out;
  float* slots = out;                // [32,8,16]
  float* attn  = out + 4096;         // [32,8,4096]

  k_prep<<<32, 256, 0, stream>>>(ln_in_w, ln_in_b, wk, wv, init_slots,
                                 ln_s_w, ln_s_b, wq,
                                 Wh, Wl, mt, qbuf, upd, Abuf, slots);
  k_proj<<<2048, 256, 0, stream>>>(inputs, Wh, Wl, mt, kproj, vproj);
  for (int it = 0; it < 3; ++it) {
    int last = (it == 2);
    k_attn<<<512, 256, 0, stream>>>(kproj, vproj, qbuf, upd, Abuf, attn, last);
    if (!last)
      k_gru<<<16, 256, 0, stream>>>(upd, Abuf, slots, qbuf,
                                    w_ih, w_hh, b_ih, b_hh,
                                    mlp_w1, mlp_b1, mlp_w2, mlp_b2,
                                    ln_m_w, ln_m_b, ln_s_w, ln_s_b, wq);
  }
  k_final<<<256, 256, 0, stream>>>(upd, Abuf, slots, qbuf, attn,
                                   w_ih, w_hh, b_ih, b_hh,
                                   mlp_w1, mlp_b1, mlp_w2, mlp_b2,
                                   ln_m_w, ln_m_b, ln_s_w, ln_s_b, wq);
}

// Round 10
// 288.466 us; speedup vs baseline: 1.0379x; 1.0379x over previous
//
#include <hip/hip_runtime.h>
#include <cstddef>

// Problem constants: B=32, N=4096, D=256, K=8 slots, S=16, H=128, 3 iters.

typedef unsigned short ushort_t;
typedef __attribute__((ext_vector_type(8))) short short8;   // 8 bf16 = 4 VGPRs
typedef __attribute__((ext_vector_type(4))) float f32x4;

__device__ __forceinline__ float sigmoid_f(float x){ return 1.f/(1.f+__expf(-x)); }
__device__ __forceinline__ float tanh_f(float x){ return 1.f - 2.f/(__expf(2.f*x)+1.f); }

// fp32 -> bf16 (RNE), as raw bits (weights + mt consistency)
__device__ __forceinline__ ushort_t f2bf(float x){
  unsigned u = __float_as_uint(x);
  return (ushort_t)((u + 0x7FFFu + ((u>>16)&1u)) >> 16);
}
__device__ __forceinline__ float bf2f(ushort_t b){
  return __uint_as_float(((unsigned)b) << 16);
}
// truncation hi/lo split (cheap: AND/SUB/SHR), combined rel err ~2^-17
__device__ __forceinline__ void split_bf(float v, short& hi, short& lo){
  unsigned u = __float_as_uint(v);
  hi = (short)(u >> 16);
  float hf = __uint_as_float(u & 0xFFFF0000u);
  lo = (short)(__float_as_uint(v - hf) >> 16);
}

// ---------------- K0: prep (bf16-split weights, init slots, q1, zeros) -----
__global__ __launch_bounds__(256) void k_prep(
    const float* __restrict__ lnw, const float* __restrict__ lnb,
    const float* __restrict__ wk, const float* __restrict__ wv,
    const float* __restrict__ init_slots,
    const float* __restrict__ ln_s_w, const float* __restrict__ ln_s_b,
    const float* __restrict__ wq,
    ushort_t* __restrict__ Wh, ushort_t* __restrict__ Wl,
    float* __restrict__ mt,
    float* __restrict__ qbuf, float* __restrict__ upd, float* __restrict__ Abuf,
    float* __restrict__ slots_out)
{
  int t = threadIdx.x;
  int i = blockIdx.x*256 + t;          // 32*256 == 8192 exactly
  {
    int s = i >> 8, d = i & 255;
    float w = (s < 16) ? wk[s*256+d] : wv[(s-16)*256+d];
    float w0 = lnw[d]*w;
    ushort_t hb = f2bf(w0);
    ushort_t lb = f2bf(w0 - bf2f(hb));
    Wh[i] = hb; Wl[i] = lb;
  }
  if (blockIdx.x != 0) return;
  // m[s] from QUANTIZED weights; t[s] exact fp32
  {
    int s = t >> 3, j = t & 7;
    float m = 0.f, tv = 0.f;
    for (int d = j; d < 256; d += 8) {
      float w = (s < 16) ? wk[s*256+d] : wv[(s-16)*256+d];
      float w0 = lnw[d]*w;
      ushort_t hb = f2bf(w0);
      float hf = bf2f(hb);
      float lf = bf2f(f2bf(w0 - hf));
      m  += hf + lf;
      tv  = fmaf(lnb[d], w, tv);
    }
    m += __shfl_xor(m,1);  m += __shfl_xor(m,2);  m += __shfl_xor(m,4);
    tv += __shfl_xor(tv,1); tv += __shfl_xor(tv,2); tv += __shfl_xor(tv,4);
    if (j == 0) { mt[s] = m; mt[32+s] = tv; }
  }
  #pragma unroll
  for (int j2 = 0; j2 < 16; ++j2) {
    slots_out[t*16+j2] = init_slots[t*16+j2];
    upd[t*16+j2] = 0.f;
  }
  Abuf[t] = 0.f;
  // q for iteration 1: thread t = (b,k) row
  float sl[16];
  #pragma unroll
  for (int j2 = 0; j2 < 16; ++j2) sl[j2] = init_slots[t*16+j2];
  float mu = 0.f;
  #pragma unroll
  for (int j2 = 0; j2 < 16; ++j2) mu += sl[j2];
  mu *= (1.f/16.f);
  float var = 0.f;
  #pragma unroll
  for (int j2 = 0; j2 < 16; ++j2) { float d = sl[j2]-mu; var = fmaf(d,d,var); }
  var *= (1.f/16.f);
  float rstd = rsqrtf(var + 1e-5f);
  float y[16];
  #pragma unroll
  for (int j2 = 0; j2 < 16; ++j2) y[j2] = (sl[j2]-mu)*rstd*ln_s_w[j2] + ln_s_b[j2];
  #pragma unroll
  for (int tq = 0; tq < 16; ++tq) {
    float q = 0.f;
    #pragma unroll
    for (int s2 = 0; s2 < 16; ++s2) q = fmaf(y[s2], wq[tq*16+s2], q);
    qbuf[t*16+tq] = q;
  }
}

// ---------------- K1: fused LayerNorm + K/V projection (weights in LDS) ----
// The R6/R8/R9 invariant limiter was the per-kk GLOBAL weight-frag loads
// (32 KB footprint == L1 size, thrashed by the x stream -> ~400cyc L2 hits,
// poorly hidden at 2 blocks/CU). Fix: stage Wh|Wl into LDS once per block
// (padded row stride 264 halfwords -> frag ds_read_b128 starts spread over
// all 8 bank-quads = structural floor). x reverts to DIRECT global loads
// (R6-style; R8/R9 proved the x-path is not the limiter): per kk each row
// reads one 128 B-contiguous segment. LDS 33.8 KB -> 4 blocks/CU (2x R9
// occupancy). mfma_f32_16x16x32_bf16, hi/lo split (3 passes), LN folded at
// epilogue via quad shuffles.
__global__ __launch_bounds__(256, 4) void k_proj(
    const float* __restrict__ x, const ushort_t* __restrict__ Wh,
    const ushort_t* __restrict__ Wl, const float* __restrict__ mt,
    float* __restrict__ kout, float* __restrict__ vout)
{
  __shared__ ushort_t wlds[64*264];   // 64 rows x 256 hw (+8 pad) = 33 KiB
  int t = threadIdx.x;
  int lane = t & 63;
  int p = __builtin_amdgcn_readfirstlane(t >> 6);
  int m = lane & 15, quad = lane >> 4;
  int r0 = blockIdx.x*64;

  // stage weights: 8192 words (Wh 16 KB then Wl 16 KB), coalesced reads,
  // LDS writes walk consecutive words within a row -> conflict-free.
  {
    const unsigned* srcH = (const unsigned*)Wh;
    const unsigned* srcL = (const unsigned*)Wl;
    unsigned* dst = (unsigned*)wlds;
    #pragma unroll
    for (int i0 = 0; i0 < 8192; i0 += 256) {
      int i = i0 + t;
      int r = i >> 7, w = i & 127;          // 128 words per 256-hw row
      unsigned v = (r < 32) ? srcH[r*128 + w] : srcL[(r-32)*128 + w];
      dst[r*132 + w] = v;
    }
  }
  __syncthreads();

  // frag rows in LDS: hk=m, hv=16+m, lk=32+m, lv=48+m; offset kk*32+quad*8 hw
  const ushort_t* rhk = wlds + (size_t)m*264 + quad*8;
  const ushort_t* rhv = wlds + (size_t)(16+m)*264 + quad*8;
  const ushort_t* rlk = wlds + (size_t)(32+m)*264 + quad*8;
  const ushort_t* rlv = wlds + (size_t)(48+m)*264 + quad*8;

  const float* xr = x + (size_t)(r0 + p*16 + m)*256 + quad*8;

  f32x4 acck = {0.f,0.f,0.f,0.f}, accv = {0.f,0.f,0.f,0.f};
  float sum = 0.f, sumsq = 0.f;

  #pragma unroll
  for (int kk = 0; kk < 8; ++kk) {
    float4 a0 = *(const float4*)(xr + kk*32);
    float4 a1 = *(const float4*)(xr + kk*32 + 4);
    short8 bh_k = *(const short8*)(rhk + kk*32);
    short8 bh_v = *(const short8*)(rhv + kk*32);
    short8 bl_k = *(const short8*)(rlk + kk*32);
    short8 bl_v = *(const short8*)(rlv + kk*32);
    float xv[8] = {a0.x,a0.y,a0.z,a0.w, a1.x,a1.y,a1.z,a1.w};
    short8 ah, al;
    #pragma unroll
    for (int j = 0; j < 8; ++j) {
      float v = xv[j];
      sum += v; sumsq = fmaf(v, v, sumsq);
      short h_, l_;
      split_bf(v, h_, l_);
      ah[j] = h_; al[j] = l_;
    }
    acck = __builtin_amdgcn_mfma_f32_16x16x32_bf16(ah, bh_k, acck, 0, 0, 0);
    accv = __builtin_amdgcn_mfma_f32_16x16x32_bf16(ah, bh_v, accv, 0, 0, 0);
    acck = __builtin_amdgcn_mfma_f32_16x16x32_bf16(al, bh_k, acck, 0, 0, 0);
    accv = __builtin_amdgcn_mfma_f32_16x16x32_bf16(al, bh_v, accv, 0, 0, 0);
    acck = __builtin_amdgcn_mfma_f32_16x16x32_bf16(ah, bl_k, acck, 0, 0, 0);
    accv = __builtin_amdgcn_mfma_f32_16x16x32_bf16(ah, bl_v, accv, 0, 0, 0);
  }

  // full row stats (each quad covered 64 of 256 cols)
  sum   += __shfl_xor(sum, 16);  sum   += __shfl_xor(sum, 32);
  sumsq += __shfl_xor(sumsq, 16); sumsq += __shfl_xor(sumsq, 32);

  float mtk  = mt[m],    mtv  = mt[16+m];
  float mtkb = mt[32+m], mtvb = mt[48+m];
  #pragma unroll
  for (int r = 0; r < 4; ++r) {
    int row = quad*4 + r;                  // C row within the wave tile
    float s_ = __shfl(sum,   row);
    float q_ = __shfl(sumsq, row);
    float mu = s_*(1.f/256.f);
    float var = q_*(1.f/256.f) - mu*mu;
    float rstd = rsqrtf(var + 1e-5f);
    float ok = fmaf(rstd, acck[r] - mu*mtk, mtkb);
    float ov = fmaf(rstd, accv[r] - mu*mtv, mtvb);
    size_t grow = (size_t)(r0 + p*16 + row)*16 + m;
    kout[grow] = ok;
    vout[grow] = ov;
  }
}

// ---------------- K2: logits + softmax-over-slots + MFMA update ------------
// (R8 version, verified.) k direct global->regs; v/p staged as bf16 hi/lo
// transposed tiles (stride 264); updates = P.V via 24 MFMA in wave 0.
__global__ __launch_bounds__(256) void k_attn(
    const float* __restrict__ kproj, const float* __restrict__ vproj,
    const float* __restrict__ qbuf,
    float* __restrict__ upd, float* __restrict__ Abuf,
    float* __restrict__ attn_out, int write_attn)
{
  __shared__ ushort_t vt[32*264];   // rows 0..15 = v_hi[s][n], 16..31 = v_lo
  __shared__ ushort_t pt[32*264];   // rows 0..7 = p_hi[kk][n], 16..23 = p_lo
  __shared__ float qs[128];
  __shared__ float apart[4][8];
  int b = blockIdx.x >> 4;
  int n0 = (blockIdx.x & 15) * 256;
  int t = threadIdx.x;
  int w = t >> 6, lane = t & 63;

  if (t < 128) qs[t] = qbuf[b*128 + t];

  const float* kr = kproj + ((size_t)(b*4096 + n0 + t))*16;
  const float* vr = vproj + ((size_t)(b*4096 + n0 + t))*16;
  float kv[16], vv[16];
  #pragma unroll
  for (int j = 0; j < 16; j += 4) {
    float4 f = *(const float4*)(kr+j);
    kv[j]=f.x; kv[j+1]=f.y; kv[j+2]=f.z; kv[j+3]=f.w;
    float4 g = *(const float4*)(vr+j);
    vv[j]=g.x; vv[j+1]=g.y; vv[j+2]=g.z; vv[j+3]=g.w;
  }
  #pragma unroll
  for (int s = 0; s < 16; ++s) {
    short h_, l_;
    split_bf(vv[s], h_, l_);
    vt[s*264 + t] = (ushort_t)h_;
    vt[(16+s)*264 + t] = (ushort_t)l_;
  }
  __syncthreads();   // qs ready

  float p8[8];
  {
    float lg[8];
    #pragma unroll
    for (int kk = 0; kk < 8; ++kk) {
      float a = 0.f;
      #pragma unroll
      for (int s = 0; s < 16; ++s) a = fmaf(qs[kk*16+s], kv[s], a);
      lg[kk] = a*0.25f;  // scale = 16^-0.5
    }
    float mx = lg[0];
    #pragma unroll
    for (int kk = 1; kk < 8; ++kk) mx = fmaxf(mx, lg[kk]);
    float se = 0.f;
    #pragma unroll
    for (int kk = 0; kk < 8; ++kk) { lg[kk] = __expf(lg[kk]-mx); se += lg[kk]; }
    float inv = 1.f/se;
    #pragma unroll
    for (int kk = 0; kk < 8; ++kk) {
      float pv = fmaf(lg[kk], inv, 1e-8f);   // softmax + EPS (pre-renorm)
      p8[kk] = pv;
      if (write_attn) attn_out[((size_t)(b*8+kk))*4096 + n0 + t] = pv;
    }
  }
  #pragma unroll
  for (int kk = 0; kk < 8; ++kk) {
    float r = p8[kk];
    r += __shfl_xor(r, 1);  r += __shfl_xor(r, 2);  r += __shfl_xor(r, 4);
    r += __shfl_xor(r, 8);  r += __shfl_xor(r, 16); r += __shfl_xor(r, 32);
    if (lane == 0) apart[w][kk] = r;
  }
  #pragma unroll
  for (int kk = 0; kk < 8; ++kk) {
    short h_, l_;
    split_bf(p8[kk], h_, l_);
    pt[kk*264 + t] = (ushort_t)h_;
    pt[(16+kk)*264 + t] = (ushort_t)l_;
  }
  __syncthreads();

  if (t < 8)
    atomicAdd(Abuf + b*8 + t,
              apart[0][t] + apart[1][t] + apart[2][t] + apart[3][t]);

  if (w == 0) {   // wave 0: updates = P . V via MFMA
    int mm = lane & 15, quad = lane >> 4;
    const short8 z8 = {0,0,0,0,0,0,0,0};
    f32x4 acc = {0.f,0.f,0.f,0.f};
    #pragma unroll
    for (int c = 0; c < 8; ++c) {
      int k0 = c*32 + quad*8;
      short8 ah = (mm < 8) ? *(const short8*)&pt[mm*264 + k0]      : z8;
      short8 al = (mm < 8) ? *(const short8*)&pt[(16+mm)*264 + k0] : z8;
      short8 bh = *(const short8*)&vt[mm*264 + k0];
      short8 bl = *(const short8*)&vt[(16+mm)*264 + k0];
      acc = __builtin_amdgcn_mfma_f32_16x16x32_bf16(ah, bh, acc, 0, 0, 0);
      acc = __builtin_amdgcn_mfma_f32_16x16x32_bf16(al, bh, acc, 0, 0, 0);
      acc = __builtin_amdgcn_mfma_f32_16x16x32_bf16(ah, bl, acc, 0, 0, 0);
    }
    int s = lane & 15;
    #pragma unroll
    for (int r = 0; r < 4; ++r) {
      int kk = quad*4 + r;
      if (kk < 8) atomicAdd(upd + (b*8+kk)*16 + s, acc[r]);
    }
  }
}

// -------- GRU cell + LN + MLP body (shared by k_gru and k_final) -----------
__device__ __forceinline__ void gru_body(
    int bk, int s, int laneBase, int prep_next,
    float* upd, float* Abuf, float* slots, float* qbuf,
    const float* s_wih, const float* s_whh,
    const float* s_bih, const float* s_bhh,
    const float* s_w1, const float* s_b1,
    const float* s_w2, const float* s_b2,
    const float* s_lnmw, const float* s_lnmb,
    const float* s_lnsw, const float* s_lnsb, const float* s_wq)
{
  float inv = 1.f / Abuf[bk];
  float u[16], h[16];
  #pragma unroll
  for (int j = 0; j < 16; ++j) {
    u[j] = upd[bk*16+j] * inv;
    h[j] = slots[bk*16+j];
  }
  float hs = slots[bk*16+s];

  float gir = s_bih[s],  giz = s_bih[16+s], gin = s_bih[32+s];
  float ghr = s_bhh[s],  ghz = s_bhh[16+s], ghn = s_bhh[32+s];
  #pragma unroll
  for (int j = 0; j < 16; ++j) {
    gir = fmaf(u[j], s_wih[s*17+j], gir);
    giz = fmaf(u[j], s_wih[(16+s)*17+j], giz);
    gin = fmaf(u[j], s_wih[(32+s)*17+j], gin);
    ghr = fmaf(h[j], s_whh[s*17+j], ghr);
    ghz = fmaf(h[j], s_whh[(16+s)*17+j], ghz);
    ghn = fmaf(h[j], s_whh[(32+s)*17+j], ghn);
  }
  float rr = sigmoid_f(gir + ghr);
  float zz = sigmoid_f(giz + ghz);
  float nn = tanh_f(gin + rr*ghn);
  float hn = (1.f-zz)*nn + zz*hs;

  float ssum = hn;
  #pragma unroll
  for (int mm = 1; mm < 16; mm <<= 1) ssum += __shfl_xor(ssum, mm);
  float mu = ssum*(1.f/16.f);
  float dv = hn - mu;
  float vs = dv*dv;
  #pragma unroll
  for (int mm = 1; mm < 16; mm <<= 1) vs += __shfl_xor(vs, mm);
  float rstd = rsqrtf(vs*(1.f/16.f) + 1e-5f);
  float y = dv*rstd*s_lnmw[s] + s_lnmb[s];

  float yv[16];
  #pragma unroll
  for (int j = 0; j < 16; ++j) yv[j] = __shfl(y, laneBase + j);

  float h1[8];
  #pragma unroll
  for (int i = 0; i < 8; ++i) {
    int jj = i*16 + s;
    float a = s_b1[jj];
    #pragma unroll
    for (int q = 0; q < 16; ++q) a = fmaf(yv[q], s_w1[jj*17+q], a);
    h1[i] = fmaxf(a, 0.f);
  }
  float o = s_b2[s];
  #pragma unroll
  for (int i = 0; i < 8; ++i) {
    #pragma unroll
    for (int sp = 0; sp < 16; ++sp) {
      float hv = __shfl(h1[i], laneBase + sp);
      o = fmaf(hv, s_w2[s*129 + i*16 + sp], o);
    }
  }
  float slot_new = hn + o;
  slots[bk*16+s] = slot_new;

  if (prep_next) {
    float ss = slot_new;
    #pragma unroll
    for (int mm = 1; mm < 16; mm <<= 1) ss += __shfl_xor(ss, mm);
    float mu2 = ss*(1.f/16.f);
    float d2 = slot_new - mu2;
    float v2 = d2*d2;
    #pragma unroll
    for (int mm = 1; mm < 16; mm <<= 1) v2 += __shfl_xor(v2, mm);
    float rstd2 = rsqrtf(v2*(1.f/16.f) + 1e-5f);
    float y2 = d2*rstd2*s_lnsw[s] + s_lnsb[s];
    float qv = 0.f;
    #pragma unroll
    for (int sp = 0; sp < 16; ++sp)
      qv = fmaf(__shfl(y2, laneBase+sp), s_wq[s*17+sp], qv);
    qbuf[bk*16+s] = qv;
    upd[bk*16+s] = 0.f;
    if (s == 0) Abuf[bk] = 0.f;
  }
}

#define GRU_STAGE_LDS()                                                      \
  __shared__ float s_wih[48*17], s_whh[48*17];                               \
  __shared__ float s_bih[48], s_bhh[48];                                     \
  __shared__ float s_w1[128*17], s_b1[128];                                  \
  __shared__ float s_w2[16*129], s_b2[16];                                   \
  __shared__ float s_lnmw[16], s_lnmb[16], s_lnsw[16], s_lnsb[16];           \
  __shared__ float s_wq[16*17];                                              \
  {                                                                          \
    int t_ = threadIdx.x;                                                    \
    for (int i = t_; i < 768; i += 256) {                                    \
      int g = i >> 4, j = i & 15;                                            \
      s_wih[g*17+j] = w_ih[i];                                               \
      s_whh[g*17+j] = w_hh[i];                                               \
    }                                                                        \
    for (int i = t_; i < 2048; i += 256) {                                   \
      int r = i >> 4, c = i & 15;                                            \
      s_w1[r*17+c] = mlp_w1[i];                                              \
      int r2 = i >> 7, c2 = i & 127;                                         \
      s_w2[r2*129+c2] = mlp_w2[i];                                           \
    }                                                                        \
    if (t_ < 48) { s_bih[t_] = b_ih[t_]; s_bhh[t_] = b_hh[t_]; }             \
    if (t_ < 128) s_b1[t_] = mlp_b1[t_];                                     \
    if (t_ < 16) {                                                           \
      s_b2[t_] = mlp_b2[t_];                                                 \
      s_lnmw[t_] = ln_m_w[t_]; s_lnmb[t_] = ln_m_b[t_];                      \
      s_lnsw[t_] = ln_s_w[t_]; s_lnsb[t_] = ln_s_b[t_];                      \
    }                                                                        \
    for (int i = t_; i < 256; i += 256) {                                    \
      int r = i >> 4, c = i & 15;                                            \
      s_wq[r*17+c] = wq[i];                                                  \
    }                                                                        \
  }                                                                          \
  __syncthreads();

// ---------------- K3: GRU for iterations 0,1 (16 blocks) -------------------
__global__ __launch_bounds__(256) void k_gru(
    float* __restrict__ upd, float* __restrict__ Abuf,
    float* __restrict__ slots, float* __restrict__ qbuf,
    const float* __restrict__ w_ih, const float* __restrict__ w_hh,
    const float* __restrict__ b_ih, const float* __restrict__ b_hh,
    const float* __restrict__ mlp_w1, const float* __restrict__ mlp_b1,
    const float* __restrict__ mlp_w2, const float* __restrict__ mlp_b2,
    const float* __restrict__ ln_m_w, const float* __restrict__ ln_m_b,
    const float* __restrict__ ln_s_w, const float* __restrict__ ln_s_b,
    const float* __restrict__ wq)
{
  GRU_STAGE_LDS()
  int t = threadIdx.x;
  int bk = blockIdx.x*16 + (t >> 4);
  int s = t & 15;
  int laneBase = (t & 63) & ~15;
  gru_body(bk, s, laneBase, 1, upd, Abuf, slots, qbuf,
           s_wih, s_whh, s_bih, s_bhh, s_w1, s_b1, s_w2, s_b2,
           s_lnmw, s_lnmb, s_lnsw, s_lnsb, s_wq);
}

// ---------------- K4: final GRU (it 2) + attn normalization (fused) --------
__global__ __launch_bounds__(256) void k_final(
    float* __restrict__ upd, float* __restrict__ Abuf,
    float* __restrict__ slots, float* __restrict__ qbuf,
    float* __restrict__ attn,
    const float* __restrict__ w_ih, const float* __restrict__ w_hh,
    const float* __restrict__ b_ih, const float* __restrict__ b_hh,
    const float* __restrict__ mlp_w1, const float* __restrict__ mlp_b1,
    const float* __restrict__ mlp_w2, const float* __restrict__ mlp_b2,
    const float* __restrict__ ln_m_w, const float* __restrict__ ln_m_b,
    const float* __restrict__ ln_s_w, const float* __restrict__ ln_s_b,
    const float* __restrict__ wq)
{
  int t = threadIdx.x;
  {
    int bk = blockIdx.x;
    float inv = 1.f / Abuf[bk];
    float4* p = (float4*)(attn + (size_t)bk*4096);
    #pragma unroll 4
    for (int i = t; i < 1024; i += 256) {
      float4 v = p[i];
      v.x *= inv; v.y *= inv; v.z *= inv; v.w *= inv;
      p[i] = v;
    }
  }
  if (blockIdx.x >= 16) return;
  GRU_STAGE_LDS()
  int bk = blockIdx.x*16 + (t >> 4);
  int s = t & 15;
  int laneBase = (t & 63) & ~15;
  gru_body(bk, s, laneBase, 0, upd, Abuf, slots, qbuf,
           s_wih, s_whh, s_bih, s_bhh, s_w1, s_b1, s_w2, s_b2,
           s_lnmw, s_lnmb, s_lnsw, s_lnsb, s_wq);
}

extern "C" void kernel_launch(void* const* d_in, const int* in_sizes, int n_in,
                              void* d_out, int out_size, void* d_ws, size_t ws_size,
                              hipStream_t stream)
{
  const float* inputs     = (const float*)d_in[0];
  const float* init_slots = (const float*)d_in[1];
  const float* ln_in_w    = (const float*)d_in[2];
  const float* ln_in_b    = (const float*)d_in[3];
  const float* ln_s_w     = (const float*)d_in[4];
  const float* ln_s_b     = (const float*)d_in[5];
  const float* ln_m_w     = (const float*)d_in[6];
  const float* ln_m_b     = (const float*)d_in[7];
  const float* wq         = (const float*)d_in[8];
  const float* wk         = (const float*)d_in[9];
  const float* wv         = (const float*)d_in[10];
  const float* w_ih       = (const float*)d_in[11];
  const float* w_hh       = (const float*)d_in[12];
  const float* b_ih       = (const float*)d_in[13];
  const float* b_hh       = (const float*)d_in[14];
  const float* mlp_w1     = (const float*)d_in[15];
  const float* mlp_b1     = (const float*)d_in[16];
  const float* mlp_w2     = (const float*)d_in[17];
  const float* mlp_b2     = (const float*)d_in[18];

  float* ws    = (float*)d_ws;
  ushort_t* Wh = (ushort_t*)ws;            // 8192 ushorts (16 KB)
  ushort_t* Wl = (ushort_t*)(ws + 4096);   // 8192 ushorts (16 KB)
  float* mt    = ws + 8192;          // 64
  float* qbuf  = ws + 8320;          // 4096
  float* upd   = ws + 12416;         // 4096
  float* Abuf  = ws + 16512;         // 256
  float* kproj = ws + 16768;         // 2097152
  float* vproj = kproj + 2097152;    // 2097152

  float* out   = (float*)d_out;
  float* slots = out;                // [32,8,16]
  float* attn  = out + 4096;         // [32,8,4096]

  k_prep<<<32, 256, 0, stream>>>(ln_in_w, ln_in_b, wk, wv, init_slots,
                                 ln_s_w, ln_s_b, wq,
                                 Wh, Wl, mt, qbuf, upd, Abuf, slots);
  k_proj<<<2048, 256, 0, stream>>>(inputs, Wh, Wl, mt, kproj, vproj);
  for (int it = 0; it < 3; ++it) {
    int last = (it == 2);
    k_attn<<<512, 256, 0, stream>>>(kproj, vproj, qbuf, upd, Abuf, attn, last);
    if (!last)
      k_gru<<<16, 256, 0, stream>>>(upd, Abuf, slots, qbuf,
                                    w_ih, w_hh, b_ih, b_hh,
                                    mlp_w1, mlp_b1, mlp_w2, mlp_b2,
                                    ln_m_w, ln_m_b, ln_s_w, ln_s_b, wq);
  }
  k_final<<<256, 256, 0, stream>>>(upd, Abuf, slots, qbuf, attn,
                                   w_ih, w_hh, b_ih, b_hh,
                                   mlp_w1, mlp_b1, mlp_w2, mlp_b2,
                                   ln_m_w, ln_m_b, ln_s_w, ln_s_b, wq);
}